// Round 4
// baseline (246.944 us; speedup 1.0000x reference)
//
#include <hip/hip_runtime.h>

typedef _Float16 half8 __attribute__((ext_vector_type(8)));
typedef _Float16 half4 __attribute__((ext_vector_type(4)));
typedef float floatx4 __attribute__((ext_vector_type(4)));

// Problem constants: B=2, N=2048, D=1024, H=16, C=3, Dh=64
// scale = 1/sqrt(64) = 0.125 exactly.

// ---------------- convert x (fp32 -> fp16), 8 elements/thread ----------------
__global__ void k_convert_x(const float* __restrict__ x, _Float16* __restrict__ xh) {
    int i = blockIdx.x * blockDim.x + threadIdx.x;
    const floatx4* xin = (const floatx4*)x;
    floatx4 a = xin[i * 2];
    floatx4 b = xin[i * 2 + 1];
    half8 h;
    h[0] = (_Float16)a[0]; h[1] = (_Float16)a[1]; h[2] = (_Float16)a[2]; h[3] = (_Float16)a[3];
    h[4] = (_Float16)b[0]; h[5] = (_Float16)b[1]; h[6] = (_Float16)b[2]; h[7] = (_Float16)b[3];
    *(half8*)&xh[i * 8] = h;
}

// ---------------- transpose + convert Wqkv [1024,3072] -> Wt fp16 [3072,1024] ----------------
__global__ void k_transpose_w(const float* __restrict__ W, _Float16* __restrict__ Wt) {
    __shared__ float tile[32][33];
    int n0 = blockIdx.x * 32, k0 = blockIdx.y * 32;
    int tx = threadIdx.x, ty = threadIdx.y;  // (32,8)
    #pragma unroll
    for (int r = 0; r < 4; ++r)
        tile[ty + r * 8][tx] = W[(k0 + ty + r * 8) * 3072 + n0 + tx];
    __syncthreads();
    #pragma unroll
    for (int r = 0; r < 4; ++r)
        Wt[(n0 + ty + r * 8) * 1024 + k0 + tx] = (_Float16)tile[tx][ty + r * 8];
}

// ---------------- negcp[b,h,n] = -sum_c coords[b,n,c]*rel_weight[h,c] ----------------
__global__ void k_negcp(const float* __restrict__ coords, const float* __restrict__ rw,
                        float* __restrict__ negcp) {
    int idx = blockIdx.x * 256 + threadIdx.x;       // over B*H*N = 65536
    int bh = idx >> 11, n = idx & 2047;
    int b = bh >> 4, h = bh & 15;
    const float* c = &coords[(b * 2048 + n) * 3];
    const float* w = &rw[h * 3];
    negcp[idx] = -(c[0] * w[0] + c[1] * w[1] + c[2] * w[2]);
}

// ---------------- mask -> fp16, S^T MFMA C-fragment layout ----------------
// half4 idx = (((qt*32+kt)*4 + w)*4 + t)*64 + lane; element i:
//   row(query) = qt*64 + w*16 + l16,  col(key) = kt*64 + t*16 + quad*4 + i
__global__ void k_prep_mask(const float* __restrict__ mask, _Float16* __restrict__ maskp) {
    int gid = blockIdx.x * 256 + threadIdx.x;       // 0 .. 1,048,575
    int lane = gid & 63, t = (gid >> 6) & 3, w = (gid >> 8) & 3;
    int kt = (gid >> 10) & 31, qt = gid >> 15;
    int quad = lane >> 4, l16 = lane & 15;
    int row = qt * 64 + w * 16 + l16;
    int col = kt * 64 + t * 16 + quad * 4;
    floatx4 m = *(const floatx4*)&mask[row * 2048 + col];
    half4 v;
    #pragma unroll
    for (int i = 0; i < 4; ++i) v[i] = (_Float16)m[i];
    ((half4*)maskp)[gid] = v;
}

// ---------------- QKV GEMM: [4096,1024] x [1024,3072] + bias, MFMA fp16 ----------------
// QK=true : cols [0,2048), computes C^T tiles (swap operands) -> half4 stores into qh/kh
// QK=false: cols [2048,3072), normal C tiles -> n-contiguous half4 stores into vt
template<bool QK>
__global__ __launch_bounds__(256) void k_gemm(
    const _Float16* __restrict__ Ah, const _Float16* __restrict__ Bt,
    const float* __restrict__ bias,
    _Float16* __restrict__ qkh, _Float16* __restrict__ vt) {
    __shared__ _Float16 As[128 * 56];
    __shared__ _Float16 Bs[128 * 56];
    int tid = threadIdx.x;
    int wave = tid >> 6, lane = tid & 63;
    int quad = lane >> 4, l16 = lane & 15;
    int m0 = blockIdx.y * 128;
    int n0 = (QK ? 0 : 2048) + blockIdx.x * 128;
    int mq = (wave >> 1) * 64, nq = (wave & 1) * 64;
    floatx4 acc[4][4] = {};
    for (int kt = 0; kt < 32; ++kt) {
        #pragma unroll
        for (int c = tid; c < 512; c += 256) {
            int row = c >> 2, c4 = c & 3;
            *(floatx4*)&As[row * 56 + c4 * 8] =
                *(const floatx4*)&Ah[(m0 + row) * 1024 + kt * 32 + c4 * 8];
            *(floatx4*)&Bs[row * 56 + c4 * 8] =
                *(const floatx4*)&Bt[(n0 + row) * 1024 + kt * 32 + c4 * 8];
        }
        __syncthreads();
        half8 af[4], bf[4];
        #pragma unroll
        for (int s = 0; s < 4; ++s)
            af[s] = *(const half8*)&As[(mq + s * 16 + l16) * 56 + quad * 8];
        #pragma unroll
        for (int s = 0; s < 4; ++s)
            bf[s] = *(const half8*)&Bs[(nq + s * 16 + l16) * 56 + quad * 8];
        #pragma unroll
        for (int ms = 0; ms < 4; ++ms)
            #pragma unroll
            for (int ns = 0; ns < 4; ++ns)
                acc[ms][ns] = QK
                    ? __builtin_amdgcn_mfma_f32_16x16x32_f16(bf[ns], af[ms], acc[ms][ns], 0, 0, 0)
                    : __builtin_amdgcn_mfma_f32_16x16x32_f16(af[ms], bf[ns], acc[ms][ns], 0, 0, 0);
        __syncthreads();
    }
    if (QK) {
        // C^T tiles: row(quad*4+i) = qkv-dim, col(l16) = x-row. half4 stores, d-contiguous.
        #pragma unroll
        for (int ns = 0; ns < 4; ++ns) {
            int col0 = n0 + nq + ns * 16 + quad * 4;       // 4 consecutive qkv-dims
            floatx4 b4 = *(const floatx4*)&bias[col0];
            int h2 = col0 >> 6;                             // 0..31 (q:0-15, k:16-31)
            int slab = ((h2 >> 4) << 5) + (h2 & 15);        // + b*16 added per-row
            int d0 = col0 & 63;
            #pragma unroll
            for (int ms = 0; ms < 4; ++ms) {
                int rowx = m0 + mq + ms * 16 + l16;
                int b = rowx >> 11, n = rowx & 2047;
                half4 hv;
                #pragma unroll
                for (int i = 0; i < 4; ++i) hv[i] = (_Float16)(acc[ms][ns][i] + b4[i]);
                *(half4*)&qkh[((size_t)(slab + b * 16) * 2048 + n) * 64 + d0] = hv;
            }
        }
    } else {
        // normal C tiles: row = x-row (4 consecutive), col = v-dim. n-contiguous half4 into vt.
        #pragma unroll
        for (int ms = 0; ms < 4; ++ms) {
            #pragma unroll
            for (int ns = 0; ns < 4; ++ns) {
                int col = n0 + nq + ns * 16 + l16;
                float bv = bias[col];
                int row0 = m0 + mq + ms * 16 + quad * 4;
                int b = row0 >> 11, n0q = row0 & 2047;
                int c2 = col - 2048;
                int h = c2 >> 6, d = c2 & 63;
                half4 hv;
                #pragma unroll
                for (int i = 0; i < 4; ++i) hv[i] = (_Float16)(acc[ms][ns][i] + bv);
                *(half4*)&vt[(((b << 4) + h) * 64 + d) * 2048 + n0q] = hv;
            }
        }
    }
}

// ---------------- flash attention, S^T formulation ----------------
// S^T = K Q^T (swap MFMA operands). P^T stays in registers: its C-layout
// (row=key=quad*4+i, col=query=l16) IS the B-operand layout of 16x16x16f16.
// O^T = V^T P^T accumulated per d-tile; epilogue is coalesced float4 stores.
__global__ __launch_bounds__(256) void k_attn(
    const _Float16* __restrict__ qh, const _Float16* __restrict__ kh,
    const _Float16* __restrict__ vt, const _Float16* __restrict__ maskp,
    const float* __restrict__ negcp, float* __restrict__ out) {
    __shared__ _Float16 Ks[64 * 72];
    __shared__ _Float16 Vs[64 * 72];   // V^T tile: [d][key]
    int tid = threadIdx.x;
    int w = tid >> 6, lane = tid & 63;
    int quad = lane >> 4, l16 = lane & 15;
    int bid = blockIdx.x;
    int qt = bid & 31, bh = bid >> 5;
    int b = bh >> 4, h = bh & 15;
    int qrow = qt * 64 + w * 16;

    // Q fragments (B-operand of S^T): lane holds query l16, dh = quad*8+j
    half8 qf[2];
    {
        const _Float16* qp = &qh[((size_t)bh * 2048 + qrow + l16) * 64];
        qf[0] = *(const half8*)&qp[quad * 8];
        qf[1] = *(const half8*)&qp[32 + quad * 8];
    }
    floatx4 o[4] = {};
    float l_part = 0.f;

    const half4* mbase = (const half4*)maskp + (size_t)((qt * 32) * 4 + w) * 4 * 64 + lane;

    for (int kt = 0; kt < 32; ++kt) {
        int kb = kt * 64;
        #pragma unroll
        for (int c = tid; c < 512; c += 256) {
            int row = c >> 3, c8 = c & 7;
            *(floatx4*)&Ks[row * 72 + c8 * 8] =
                *(const floatx4*)&kh[((size_t)bh * 2048 + kb + row) * 64 + c8 * 8];
            *(floatx4*)&Vs[row * 72 + c8 * 8] =
                *(const floatx4*)&vt[((size_t)bh * 64 + row) * 2048 + kb + c8 * 8];
        }
        // mask + coord-bias loads issued while staging drains
        const half4* mp = mbase + (size_t)kt * 1024;   // 4*4*64 half4 per kt
        half4 mload[4];
        floatx4 ncv[4];
        #pragma unroll
        for (int t = 0; t < 4; ++t) mload[t] = mp[t * 64];
        #pragma unroll
        for (int t = 0; t < 4; ++t)
            ncv[t] = *(const floatx4*)&negcp[bh * 2048 + kb + t * 16 + quad * 4];
        __syncthreads();

        // S^T tiles: A = K-frag (m=key), B = Q-frag (n=query)
        floatx4 st[4];
        #pragma unroll
        for (int t = 0; t < 4; ++t) {
            half8 k0 = *(const half8*)&Ks[(t * 16 + l16) * 72 + quad * 8];
            half8 k1 = *(const half8*)&Ks[(t * 16 + l16) * 72 + 32 + quad * 8];
            floatx4 z = {};
            z = __builtin_amdgcn_mfma_f32_16x16x32_f16(k0, qf[0], z, 0, 0, 0);
            z = __builtin_amdgcn_mfma_f32_16x16x32_f16(k1, qf[1], z, 0, 0, 0);
            st[t] = z;
        }
        // p = exp(0.125*s + mask + nc), P^T packed to half4 in-register
        half4 pt[4];
        #pragma unroll
        for (int t = 0; t < 4; ++t) {
            #pragma unroll
            for (int i = 0; i < 4; ++i) {
                float pv = __expf(fmaf(st[t][i], 0.125f, (float)mload[t][i] + ncv[t][i]));
                l_part += pv;
                pt[t][i] = (_Float16)pv;
            }
        }
        // O^T += V^T P^T : A = V^T frag (m=d, k=key quad*4+j), B = pt[t]
        #pragma unroll
        for (int dt = 0; dt < 4; ++dt) {
            #pragma unroll
            for (int t = 0; t < 4; ++t) {
                half4 vf = *(const half4*)&Vs[(dt * 16 + l16) * 72 + t * 16 + quad * 4];
                o[dt] = __builtin_amdgcn_mfma_f32_16x16x16f16(vf, pt[t], o[dt], 0, 0, 0);
            }
        }
        __syncthreads();   // protect Ks/Vs restage
    }
    // row-sum: lane has partial over its quad's 16 keys; combine across quads (2 shuffles)
    l_part += __shfl_xor(l_part, 16);
    l_part += __shfl_xor(l_part, 32);
    float inv = 1.f / l_part;
    // epilogue: O^T C-layout row = d = dt*16+quad*4+i (consecutive!), col = query = l16
    #pragma unroll
    for (int dt = 0; dt < 4; ++dt) {
        floatx4 r;
        #pragma unroll
        for (int i = 0; i < 4; ++i) r[i] = o[dt][i] * inv;
        *(floatx4*)&out[((size_t)(b * 2048 + qrow + l16)) * 1024 + h * 64 + dt * 16 + quad * 4] = r;
    }
}

extern "C" void kernel_launch(void* const* d_in, const int* in_sizes, int n_in,
                              void* d_out, int out_size, void* d_ws, size_t ws_size,
                              hipStream_t stream) {
    const float* x      = (const float*)d_in[0];
    const float* coords = (const float*)d_in[1];
    const float* mask   = (const float*)d_in[2];
    const float* Wqkv   = (const float*)d_in[3];
    const float* bqkv   = (const float*)d_in[4];
    const float* rw     = (const float*)d_in[5];
    float* out = (float*)d_out;

    // Workspace layout (byte offsets), total 40,108,032 B:
    //   xh   : [0,          8,388,608)  -- dead after gemm; maskp reuses it
    //   Wt   : [8,388,608,  14,680,064)
    //   qh   : [14,680,064, 23,068,672)   (qh and kh contiguous: qkh slab layout)
    //   kh   : [23,068,672, 31,457,280)
    //   vt   : [31,457,280, 39,845,888)
    //   ncp  : [39,845,888, 40,108,032)
    char* ws = (char*)d_ws;
    _Float16* xh    = (_Float16*)(ws);
    _Float16* maskp = (_Float16*)(ws);
    _Float16* Wt    = (_Float16*)(ws + 8388608);
    _Float16* qh    = (_Float16*)(ws + 14680064);   // qkh base (slabs 0-31: q then k)
    _Float16* kh    = (_Float16*)(ws + 23068672);
    _Float16* vt    = (_Float16*)(ws + 31457280);
    float*    ncp   = (float*)(ws + 39845888);

    k_convert_x<<<2048, 256, 0, stream>>>(x, xh);
    k_transpose_w<<<dim3(96, 32), dim3(32, 8), 0, stream>>>(Wqkv, Wt);
    k_negcp<<<256, 256, 0, stream>>>(coords, rw, ncp);
    k_gemm<true ><<<dim3(16, 32), 256, 0, stream>>>(xh, Wt, bqkv, qh, vt);
    k_gemm<false><<<dim3(8, 32),  256, 0, stream>>>(xh, Wt, bqkv, qh, vt);
    k_prep_mask<<<4096, 256, 0, stream>>>(mask, maskp);   // overwrites xh (now dead)
    k_attn<<<1024, 256, 0, stream>>>(qh, kh, vt, maskp, ncp, out);
}

// Round 5
// 224.587 us; speedup vs baseline: 1.0996x; 1.0996x over previous
//
#include <hip/hip_runtime.h>

typedef _Float16 half8 __attribute__((ext_vector_type(8)));
typedef _Float16 half4 __attribute__((ext_vector_type(4)));
typedef float floatx4 __attribute__((ext_vector_type(4)));

// Problem constants: B=2, N=2048, D=1024, H=16, C=3, Dh=64
// scale = 1/sqrt(64) = 0.125 exactly.

__device__ __forceinline__ void async16(const void* g, void* l) {
    __builtin_amdgcn_global_load_lds(
        (const __attribute__((address_space(1))) unsigned int*)g,
        (__attribute__((address_space(3))) unsigned int*)l, 16, 0, 0);
}

// ---------------- convert x (fp32 -> fp16), 8 elements/thread ----------------
__global__ void k_convert_x(const float* __restrict__ x, _Float16* __restrict__ xh) {
    int i = blockIdx.x * blockDim.x + threadIdx.x;
    const floatx4* xin = (const floatx4*)x;
    floatx4 a = xin[i * 2];
    floatx4 b = xin[i * 2 + 1];
    half8 h;
    h[0] = (_Float16)a[0]; h[1] = (_Float16)a[1]; h[2] = (_Float16)a[2]; h[3] = (_Float16)a[3];
    h[4] = (_Float16)b[0]; h[5] = (_Float16)b[1]; h[6] = (_Float16)b[2]; h[7] = (_Float16)b[3];
    *(half8*)&xh[i * 8] = h;
}

// ---------------- transpose + convert Wqkv [1024,3072] -> Wt fp16 [3072,1024] ----------------
__global__ void k_transpose_w(const float* __restrict__ W, _Float16* __restrict__ Wt) {
    __shared__ float tile[32][33];
    int n0 = blockIdx.x * 32, k0 = blockIdx.y * 32;
    int tx = threadIdx.x, ty = threadIdx.y;  // (32,8)
    #pragma unroll
    for (int r = 0; r < 4; ++r)
        tile[ty + r * 8][tx] = W[(k0 + ty + r * 8) * 3072 + n0 + tx];
    __syncthreads();
    #pragma unroll
    for (int r = 0; r < 4; ++r)
        Wt[(n0 + ty + r * 8) * 1024 + k0 + tx] = (_Float16)tile[tx][ty + r * 8];
}

// ---------------- negcp[b,h,n] = -sum_c coords[b,n,c]*rel_weight[h,c] ----------------
__global__ void k_negcp(const float* __restrict__ coords, const float* __restrict__ rw,
                        float* __restrict__ negcp) {
    int idx = blockIdx.x * 256 + threadIdx.x;       // over B*H*N = 65536
    int bh = idx >> 11, n = idx & 2047;
    int b = bh >> 4, h = bh & 15;
    const float* c = &coords[(b * 2048 + n) * 3];
    const float* w = &rw[h * 3];
    negcp[idx] = -(c[0] * w[0] + c[1] * w[1] + c[2] * w[2]);
}

// ---------------- mask -> fp16, S^T MFMA C-fragment layout ----------------
__global__ void k_prep_mask(const float* __restrict__ mask, _Float16* __restrict__ maskp) {
    int gid = blockIdx.x * 256 + threadIdx.x;       // 0 .. 1,048,575
    int lane = gid & 63, t = (gid >> 6) & 3, w = (gid >> 8) & 3;
    int kt = (gid >> 10) & 31, qt = gid >> 15;
    int quad = lane >> 4, l16 = lane & 15;
    int row = qt * 64 + w * 16 + l16;
    int col = kt * 64 + t * 16 + quad * 4;
    floatx4 m = *(const floatx4*)&mask[row * 2048 + col];
    half4 v;
    #pragma unroll
    for (int i = 0; i < 4; ++i) v[i] = (_Float16)m[i];
    ((half4*)maskp)[gid] = v;
}

// ---------------- QKV GEMM, m97-style: global_load_lds(16) + XOR-swizzled LDS ----------------
// 128x128 tile, BK=64 halves (128B rows), 16 K-iters.
// QK=true : cols [0,2048), swapped-operand MFMA -> C^T; epilogue via LDS -> [bh][n][d] half8 stores
// QK=false: cols [2048,3072), normal MFMA;        epilogue via LDS -> [bh][d][n] half8 stores
template<bool QK>
__global__ __launch_bounds__(256) void k_gemm(
    const _Float16* __restrict__ Ah, const _Float16* __restrict__ Bt,
    const float* __restrict__ bias,
    _Float16* __restrict__ qh, _Float16* __restrict__ kh, _Float16* __restrict__ vt) {
    // smem: staging As(8192 halves) + Bs(8192) = 32KB; epilogue 4 wave-slabs of 64x72 = 36KB.
    __shared__ _Float16 smem[18432];
    _Float16* As = smem;            // [128][64], unpadded, 16B-block-swizzled
    _Float16* Bs = smem + 8192;     // [128][64]
    int tid = threadIdx.x;
    int w = tid >> 6, lane = tid & 63;
    int quad = lane >> 4, l16 = lane & 15;
    int m0 = blockIdx.y * 128;
    int n0 = (QK ? 0 : 2048) + blockIdx.x * 128;
    int mq = (w >> 1) * 64, nq = (w & 1) * 64;
    int c0 = n0 + nq;                               // this wave's 64-col base (64-aligned)

    int rl = lane >> 3;                             // row within 8-row staging chunk
    int pb = lane & 7;                              // physical 16B block within 128B row
    floatx4 acc[4][4] = {};

    for (int kt = 0; kt < 16; ++kt) {
        // stage A,B: each wave 4 calls each, 8 rows/call; source block = pb ^ (row&7)
        #pragma unroll
        for (int j = 0; j < 4; ++j) {
            int row = w * 32 + j * 8 + rl;
            async16(&Ah[(size_t)(m0 + row) * 1024 + kt * 64 + ((pb ^ (row & 7)) << 3)],
                    &As[(w * 32 + j * 8) * 64]);
            async16(&Bt[(size_t)(n0 + row) * 1024 + kt * 64 + ((pb ^ (row & 7)) << 3)],
                    &Bs[(w * 32 + j * 8) * 64]);
        }
        __syncthreads();
        #pragma unroll
        for (int kc = 0; kc < 2; ++kc) {
            half8 af[4], bf[4];
            #pragma unroll
            for (int s = 0; s < 4; ++s) {
                int ra = mq + s * 16 + l16;
                af[s] = *(const half8*)&As[ra * 64 + ((((kc << 2) + quad) ^ (ra & 7)) << 3)];
                int rb = nq + s * 16 + l16;
                bf[s] = *(const half8*)&Bs[rb * 64 + ((((kc << 2) + quad) ^ (rb & 7)) << 3)];
            }
            #pragma unroll
            for (int ms = 0; ms < 4; ++ms)
                #pragma unroll
                for (int ns = 0; ns < 4; ++ns)
                    acc[ms][ns] = QK
                        ? __builtin_amdgcn_mfma_f32_16x16x32_f16(bf[ns], af[ms], acc[ms][ns], 0, 0, 0)
                        : __builtin_amdgcn_mfma_f32_16x16x32_f16(af[ms], bf[ns], acc[ms][ns], 0, 0, 0);
        }
        __syncthreads();
    }

    // ---- epilogue: stage to wave-private LDS slab (stride 72), coalesced half8 stores ----
    _Float16* Ls = smem + w * 4608;                 // 64 x 72 halves
    int b = (m0 + mq) >> 11, nbase = (m0 + mq) & 2047;
    if (QK) {
        // C^T: lane holds c = c0+ns*16+quad*4+i, n = mq+ms*16+l16. Stage [n][c].
        #pragma unroll
        for (int ns = 0; ns < 4; ++ns) {
            floatx4 b4 = *(const floatx4*)&bias[c0 + ns * 16 + quad * 4];
            #pragma unroll
            for (int ms = 0; ms < 4; ++ms) {
                half4 hv;
                #pragma unroll
                for (int i = 0; i < 4; ++i) hv[i] = (_Float16)(acc[ms][ns][i] + b4[i]);
                *(half4*)&Ls[(ms * 16 + l16) * 72 + ns * 16 + quad * 4] = hv;
            }
        }
        int h2 = c0 >> 6;                           // 0..31: q heads then k heads
        _Float16* dst = (h2 < 16 ? qh : kh) + (size_t)(((b << 4) + (h2 & 15)) * 2048) * 64;
        int d0 = pb << 3;
        #pragma unroll
        for (int rep = 0; rep < 8; ++rep) {
            int nl = rep * 8 + rl;
            half8 v = *(const half8*)&Ls[nl * 72 + d0];
            *(half8*)&dst[(size_t)(nbase + nl) * 64 + d0] = v;   // 8 lanes = 128B line
        }
    } else {
        // normal C: lane holds n = mq+ms*16+quad*4+i, c = c0+ns*16+l16. Stage [c][n].
        #pragma unroll
        for (int ns = 0; ns < 4; ++ns) {
            float bv = bias[c0 + ns * 16 + l16];
            #pragma unroll
            for (int ms = 0; ms < 4; ++ms) {
                half4 hv;
                #pragma unroll
                for (int i = 0; i < 4; ++i) hv[i] = (_Float16)(acc[ms][ns][i] + bv);
                *(half4*)&Ls[(ns * 16 + l16) * 72 + ms * 16 + quad * 4] = hv;
            }
        }
        int h = (c0 - 2048) >> 6;                   // uniform per wave; d = c_local
        _Float16* dst = vt + (size_t)(((b << 4) + h) * 64) * 2048;
        int noff = pb << 3;
        #pragma unroll
        for (int rep = 0; rep < 8; ++rep) {
            int cl = rep * 8 + rl;                  // d row
            half8 v = *(const half8*)&Ls[cl * 72 + noff];
            *(half8*)&dst[(size_t)cl * 2048 + nbase + noff] = v;
        }
    }
}

// ---------------- flash attention, S^T formulation (unchanged from R4) ----------------
__global__ __launch_bounds__(256) void k_attn(
    const _Float16* __restrict__ qh, const _Float16* __restrict__ kh,
    const _Float16* __restrict__ vt, const _Float16* __restrict__ maskp,
    const float* __restrict__ negcp, float* __restrict__ out) {
    __shared__ _Float16 Ks[64 * 72];
    __shared__ _Float16 Vs[64 * 72];   // V^T tile: [d][key]
    int tid = threadIdx.x;
    int w = tid >> 6, lane = tid & 63;
    int quad = lane >> 4, l16 = lane & 15;
    int bid = blockIdx.x;
    int qt = bid & 31, bh = bid >> 5;
    int b = bh >> 4, h = bh & 15;
    int qrow = qt * 64 + w * 16;

    half8 qf[2];
    {
        const _Float16* qp = &qh[((size_t)bh * 2048 + qrow + l16) * 64];
        qf[0] = *(const half8*)&qp[quad * 8];
        qf[1] = *(const half8*)&qp[32 + quad * 8];
    }
    floatx4 o[4] = {};
    float l_part = 0.f;

    const half4* mbase = (const half4*)maskp + (size_t)((qt * 32) * 4 + w) * 4 * 64 + lane;

    for (int kt = 0; kt < 32; ++kt) {
        int kb = kt * 64;
        #pragma unroll
        for (int c = tid; c < 512; c += 256) {
            int row = c >> 3, c8 = c & 7;
            *(floatx4*)&Ks[row * 72 + c8 * 8] =
                *(const floatx4*)&kh[((size_t)bh * 2048 + kb + row) * 64 + c8 * 8];
            *(floatx4*)&Vs[row * 72 + c8 * 8] =
                *(const floatx4*)&vt[((size_t)bh * 64 + row) * 2048 + kb + c8 * 8];
        }
        const half4* mp = mbase + (size_t)kt * 1024;
        half4 mload[4];
        floatx4 ncv[4];
        #pragma unroll
        for (int t = 0; t < 4; ++t) mload[t] = mp[t * 64];
        #pragma unroll
        for (int t = 0; t < 4; ++t)
            ncv[t] = *(const floatx4*)&negcp[bh * 2048 + kb + t * 16 + quad * 4];
        __syncthreads();

        floatx4 st[4];
        #pragma unroll
        for (int t = 0; t < 4; ++t) {
            half8 k0 = *(const half8*)&Ks[(t * 16 + l16) * 72 + quad * 8];
            half8 k1 = *(const half8*)&Ks[(t * 16 + l16) * 72 + 32 + quad * 8];
            floatx4 z = {};
            z = __builtin_amdgcn_mfma_f32_16x16x32_f16(k0, qf[0], z, 0, 0, 0);
            z = __builtin_amdgcn_mfma_f32_16x16x32_f16(k1, qf[1], z, 0, 0, 0);
            st[t] = z;
        }
        half4 pt[4];
        #pragma unroll
        for (int t = 0; t < 4; ++t) {
            #pragma unroll
            for (int i = 0; i < 4; ++i) {
                float pv = __expf(fmaf(st[t][i], 0.125f, (float)mload[t][i] + ncv[t][i]));
                l_part += pv;
                pt[t][i] = (_Float16)pv;
            }
        }
        #pragma unroll
        for (int dt = 0; dt < 4; ++dt) {
            #pragma unroll
            for (int t = 0; t < 4; ++t) {
                half4 vf = *(const half4*)&Vs[(dt * 16 + l16) * 72 + t * 16 + quad * 4];
                o[dt] = __builtin_amdgcn_mfma_f32_16x16x16f16(vf, pt[t], o[dt], 0, 0, 0);
            }
        }
        __syncthreads();
    }
    l_part += __shfl_xor(l_part, 16);
    l_part += __shfl_xor(l_part, 32);
    float inv = 1.f / l_part;
    #pragma unroll
    for (int dt = 0; dt < 4; ++dt) {
        floatx4 r;
        #pragma unroll
        for (int i = 0; i < 4; ++i) r[i] = o[dt][i] * inv;
        *(floatx4*)&out[((size_t)(b * 2048 + qrow + l16)) * 1024 + h * 64 + dt * 16 + quad * 4] = r;
    }
}

extern "C" void kernel_launch(void* const* d_in, const int* in_sizes, int n_in,
                              void* d_out, int out_size, void* d_ws, size_t ws_size,
                              hipStream_t stream) {
    const float* x      = (const float*)d_in[0];
    const float* coords = (const float*)d_in[1];
    const float* mask   = (const float*)d_in[2];
    const float* Wqkv   = (const float*)d_in[3];
    const float* bqkv   = (const float*)d_in[4];
    const float* rw     = (const float*)d_in[5];
    float* out = (float*)d_out;

    char* ws = (char*)d_ws;
    _Float16* xh    = (_Float16*)(ws);               // dead after gemm; maskp reuses
    _Float16* maskp = (_Float16*)(ws);
    _Float16* Wt    = (_Float16*)(ws + 8388608);
    _Float16* qh    = (_Float16*)(ws + 14680064);
    _Float16* kh    = (_Float16*)(ws + 23068672);
    _Float16* vt    = (_Float16*)(ws + 31457280);
    float*    ncp   = (float*)(ws + 39845888);

    k_convert_x<<<2048, 256, 0, stream>>>(x, xh);
    k_transpose_w<<<dim3(96, 32), dim3(32, 8), 0, stream>>>(Wqkv, Wt);
    k_negcp<<<256, 256, 0, stream>>>(coords, rw, ncp);
    k_gemm<true ><<<dim3(16, 32), 256, 0, stream>>>(xh, Wt, bqkv, qh, kh, vt);
    k_gemm<false><<<dim3(8, 32),  256, 0, stream>>>(xh, Wt, bqkv, qh, kh, vt);
    k_prep_mask<<<4096, 256, 0, stream>>>(mask, maskp);   // overwrites xh (now dead)
    k_attn<<<1024, 256, 0, stream>>>(qh, kh, vt, maskp, ncp, out);
}

// Round 6
// 213.431 us; speedup vs baseline: 1.1570x; 1.0523x over previous
//
#include <hip/hip_runtime.h>

typedef _Float16 half8 __attribute__((ext_vector_type(8)));
typedef _Float16 half4 __attribute__((ext_vector_type(4)));
typedef float floatx4 __attribute__((ext_vector_type(4)));

// Problem constants: B=2, N=2048, D=1024, H=16, C=3, Dh=64
// scale = 1/sqrt(64) = 0.125 exactly.

__device__ __forceinline__ void async16(const void* g, void* l) {
    __builtin_amdgcn_global_load_lds(
        (const __attribute__((address_space(1))) unsigned int*)g,
        (__attribute__((address_space(3))) unsigned int*)l, 16, 0, 0);
}

// ---------------- convert x (fp32 -> fp16), 8 elements/thread ----------------
__global__ void k_convert_x(const float* __restrict__ x, _Float16* __restrict__ xh) {
    int i = blockIdx.x * blockDim.x + threadIdx.x;
    const floatx4* xin = (const floatx4*)x;
    floatx4 a = xin[i * 2];
    floatx4 b = xin[i * 2 + 1];
    half8 h;
    h[0] = (_Float16)a[0]; h[1] = (_Float16)a[1]; h[2] = (_Float16)a[2]; h[3] = (_Float16)a[3];
    h[4] = (_Float16)b[0]; h[5] = (_Float16)b[1]; h[6] = (_Float16)b[2]; h[7] = (_Float16)b[3];
    *(half8*)&xh[i * 8] = h;
}

// ---------------- transpose + convert Wqkv [1024,3072] -> Wt fp16 [3072,1024] ----------------
__global__ void k_transpose_w(const float* __restrict__ W, _Float16* __restrict__ Wt) {
    __shared__ float tile[32][33];
    int n0 = blockIdx.x * 32, k0 = blockIdx.y * 32;
    int tx = threadIdx.x, ty = threadIdx.y;  // (32,8)
    #pragma unroll
    for (int r = 0; r < 4; ++r)
        tile[ty + r * 8][tx] = W[(k0 + ty + r * 8) * 3072 + n0 + tx];
    __syncthreads();
    #pragma unroll
    for (int r = 0; r < 4; ++r)
        Wt[(n0 + ty + r * 8) * 1024 + k0 + tx] = (_Float16)tile[tx][ty + r * 8];
}

// ---------------- negcp[b,h,n] = -sum_c coords[b,n,c]*rel_weight[h,c] ----------------
__global__ void k_negcp(const float* __restrict__ coords, const float* __restrict__ rw,
                        float* __restrict__ negcp) {
    int idx = blockIdx.x * 256 + threadIdx.x;       // over B*H*N = 65536
    int bh = idx >> 11, n = idx & 2047;
    int b = bh >> 4, h = bh & 15;
    const float* c = &coords[(b * 2048 + n) * 3];
    const float* w = &rw[h * 3];
    negcp[idx] = -(c[0] * w[0] + c[1] * w[1] + c[2] * w[2]);
}

// ---------------- mask -> fp16, S^T MFMA C-fragment layout ----------------
__global__ void k_prep_mask(const float* __restrict__ mask, _Float16* __restrict__ maskp) {
    int gid = blockIdx.x * 256 + threadIdx.x;       // 0 .. 1,048,575
    int lane = gid & 63, t = (gid >> 6) & 3, w = (gid >> 8) & 3;
    int kt = (gid >> 10) & 31, qt = gid >> 15;
    int quad = lane >> 4, l16 = lane & 15;
    int row = qt * 64 + w * 16 + l16;
    int col = kt * 64 + t * 16 + quad * 4;
    floatx4 m = *(const floatx4*)&mask[row * 2048 + col];
    half4 v;
    #pragma unroll
    for (int i = 0; i < 4; ++i) v[i] = (_Float16)m[i];
    ((half4*)maskp)[gid] = v;
}

// ---------------- fused QKV GEMM: 768 blocks, n0 = bx*128 over all 3072 cols ----------------
// QK (n0<2048): swapped-operand MFMA -> C^T; epilogue -> [bh][n][d] half8 stores
// V  (n0>=2048): normal MFMA;           epilogue -> [bh][d][n] half8 stores
__global__ __launch_bounds__(256) void k_gemm(
    const _Float16* __restrict__ Ah, const _Float16* __restrict__ Bt,
    const float* __restrict__ bias,
    _Float16* __restrict__ qh, _Float16* __restrict__ kh, _Float16* __restrict__ vt) {
    __shared__ _Float16 smem[18432];
    _Float16* As = smem;            // [128][64], unpadded, 16B-block-swizzled
    _Float16* Bs = smem + 8192;     // [128][64]
    int tid = threadIdx.x;
    int w = tid >> 6, lane = tid & 63;
    int quad = lane >> 4, l16 = lane & 15;
    int m0 = blockIdx.y * 128;
    int n0 = blockIdx.x * 128;
    bool QK = n0 < 2048;
    int mq = (w >> 1) * 64, nq = (w & 1) * 64;
    int c0 = n0 + nq;

    int rl = lane >> 3;                             // row within 8-row staging chunk
    int pb = lane & 7;                              // physical 16B block within 128B row
    floatx4 acc[4][4] = {};

    for (int kt = 0; kt < 16; ++kt) {
        #pragma unroll
        for (int j = 0; j < 4; ++j) {
            int row = w * 32 + j * 8 + rl;
            async16(&Ah[(size_t)(m0 + row) * 1024 + kt * 64 + ((pb ^ (row & 7)) << 3)],
                    &As[(w * 32 + j * 8) * 64]);
            async16(&Bt[(size_t)(n0 + row) * 1024 + kt * 64 + ((pb ^ (row & 7)) << 3)],
                    &Bs[(w * 32 + j * 8) * 64]);
        }
        __syncthreads();
        #pragma unroll
        for (int kc = 0; kc < 2; ++kc) {
            half8 af[4], bf[4];
            #pragma unroll
            for (int s = 0; s < 4; ++s) {
                int ra = mq + s * 16 + l16;
                af[s] = *(const half8*)&As[ra * 64 + ((((kc << 2) + quad) ^ (ra & 7)) << 3)];
                int rb = nq + s * 16 + l16;
                bf[s] = *(const half8*)&Bs[rb * 64 + ((((kc << 2) + quad) ^ (rb & 7)) << 3)];
            }
            if (QK) {
                #pragma unroll
                for (int ms = 0; ms < 4; ++ms)
                    #pragma unroll
                    for (int ns = 0; ns < 4; ++ns)
                        acc[ms][ns] = __builtin_amdgcn_mfma_f32_16x16x32_f16(bf[ns], af[ms], acc[ms][ns], 0, 0, 0);
            } else {
                #pragma unroll
                for (int ms = 0; ms < 4; ++ms)
                    #pragma unroll
                    for (int ns = 0; ns < 4; ++ns)
                        acc[ms][ns] = __builtin_amdgcn_mfma_f32_16x16x32_f16(af[ms], bf[ns], acc[ms][ns], 0, 0, 0);
            }
        }
        __syncthreads();
    }

    // ---- epilogue: stage to wave-private LDS slab (stride 72), coalesced half8 stores ----
    _Float16* Ls = smem + w * 4608;                 // 64 x 72 halves
    int b = (m0 + mq) >> 11, nbase = (m0 + mq) & 2047;
    if (QK) {
        #pragma unroll
        for (int ns = 0; ns < 4; ++ns) {
            floatx4 b4 = *(const floatx4*)&bias[c0 + ns * 16 + quad * 4];
            #pragma unroll
            for (int ms = 0; ms < 4; ++ms) {
                half4 hv;
                #pragma unroll
                for (int i = 0; i < 4; ++i) hv[i] = (_Float16)(acc[ms][ns][i] + b4[i]);
                *(half4*)&Ls[(ms * 16 + l16) * 72 + ns * 16 + quad * 4] = hv;
            }
        }
        int h2 = c0 >> 6;                           // 0..31: q heads then k heads
        _Float16* dst = (h2 < 16 ? qh : kh) + (size_t)(((b << 4) + (h2 & 15)) * 2048) * 64;
        int d0 = pb << 3;
        #pragma unroll
        for (int rep = 0; rep < 8; ++rep) {
            int nl = rep * 8 + rl;
            half8 v = *(const half8*)&Ls[nl * 72 + d0];
            *(half8*)&dst[(size_t)(nbase + nl) * 64 + d0] = v;
        }
    } else {
        #pragma unroll
        for (int ns = 0; ns < 4; ++ns) {
            float bv = bias[c0 + ns * 16 + l16];
            #pragma unroll
            for (int ms = 0; ms < 4; ++ms) {
                half4 hv;
                #pragma unroll
                for (int i = 0; i < 4; ++i) hv[i] = (_Float16)(acc[ms][ns][i] + bv);
                *(half4*)&Ls[(ns * 16 + l16) * 72 + ms * 16 + quad * 4] = hv;
            }
        }
        int h = (c0 - 2048) >> 6;
        _Float16* dst = vt + (size_t)(((b << 4) + h) * 64) * 2048;
        int noff = pb << 3;
        #pragma unroll
        for (int rep = 0; rep < 8; ++rep) {
            int cl = rep * 8 + rl;
            half8 v = *(const half8*)&Ls[cl * 72 + noff];
            *(half8*)&dst[(size_t)cl * 2048 + nbase + noff] = v;
        }
    }
}

// ---------------- flash attention, S^T form + double-buffered async staging ----------------
// One barrier/iter: stage(kt+1) issued right after the barrier; its vmcnt(0) drain happens
// at the NEXT barrier, a full compute phase later. XOR-swizzled unpadded LDS tiles.
__global__ __launch_bounds__(256) void k_attn(
    const _Float16* __restrict__ qh, const _Float16* __restrict__ kh,
    const _Float16* __restrict__ vt, const _Float16* __restrict__ maskp,
    const float* __restrict__ negcp, float* __restrict__ out) {
    __shared__ _Float16 KV[2][8192];   // per buf: K [0,4096) halves, V [4096,8192); 32 KB total
    int tid = threadIdx.x;
    int w = tid >> 6, lane = tid & 63;
    int quad = lane >> 4, l16 = lane & 15;
    int rl = lane >> 3, pb = lane & 7;
    int bid = blockIdx.x;
    int qt = bid & 31, bh = bid >> 5;
    int b = bh >> 4, h = bh & 15;
    int qrow = qt * 64 + w * 16;

    half8 qf[2];
    {
        const _Float16* qp = &qh[((size_t)bh * 2048 + qrow + l16) * 64];
        qf[0] = *(const half8*)&qp[quad * 8];
        qf[1] = *(const half8*)&qp[32 + quad * 8];
    }
    floatx4 o[4] = {};
    float l_part = 0.f;

    const half4* mbase = (const half4*)maskp + (size_t)((qt * 32) * 4 + w) * 4 * 64 + lane;
    const _Float16* khb = kh + (size_t)bh * 2048 * 64;
    const _Float16* vtb = vt + (size_t)bh * 64 * 2048;

    // stage tile kt into buf: K rows (64x128B) and V rows, swizzled 16B source blocks
    #define STAGE(ktv, buf) {                                                         \
        int kb_ = (ktv) * 64;                                                         \
        _Float16* Kd = &KV[buf][0];                                                   \
        _Float16* Vd = &KV[buf][4096];                                                \
        _Pragma("unroll")                                                             \
        for (int j = 0; j < 2; ++j) {                                                 \
            int row = w * 16 + j * 8 + rl;                                            \
            async16(&khb[(size_t)(kb_ + row) * 64 + ((pb ^ (row & 7)) << 3)],         \
                    &Kd[(w * 16 + j * 8) * 64]);                                      \
            async16(&vtb[(size_t)row * 2048 + kb_ + ((pb ^ (row & 7)) << 3)],         \
                    &Vd[(w * 16 + j * 8) * 64]);                                      \
        }                                                                             \
    }

    STAGE(0, 0);
    for (int kt = 0; kt < 32; ++kt) {
        int cur = kt & 1;
        __syncthreads();                 // drains stage(kt) (issued one full iter ago)
        if (kt < 31) STAGE(kt + 1, cur ^ 1);
        int kb = kt * 64;
        const half4* mp = mbase + (size_t)kt * 1024;
        half4 mload[4];
        floatx4 ncv[4];
        #pragma unroll
        for (int t = 0; t < 4; ++t) mload[t] = mp[t * 64];
        #pragma unroll
        for (int t = 0; t < 4; ++t)
            ncv[t] = *(const floatx4*)&negcp[bh * 2048 + kb + t * 16 + quad * 4];

        const _Float16* Ksc = &KV[cur][0];
        const _Float16* Vsc = &KV[cur][4096];
        floatx4 st[4];
        #pragma unroll
        for (int t = 0; t < 4; ++t) {
            int r = t * 16 + l16;
            half8 k0 = *(const half8*)&Ksc[r * 64 + ((quad ^ (r & 7)) << 3)];
            half8 k1 = *(const half8*)&Ksc[r * 64 + (((quad + 4) ^ (r & 7)) << 3)];
            floatx4 z = {};
            z = __builtin_amdgcn_mfma_f32_16x16x32_f16(k0, qf[0], z, 0, 0, 0);
            z = __builtin_amdgcn_mfma_f32_16x16x32_f16(k1, qf[1], z, 0, 0, 0);
            st[t] = z;
        }
        half4 pt[4];
        #pragma unroll
        for (int t = 0; t < 4; ++t) {
            #pragma unroll
            for (int i = 0; i < 4; ++i) {
                float pv = __expf(fmaf(st[t][i], 0.125f, (float)mload[t][i] + ncv[t][i]));
                l_part += pv;
                pt[t][i] = (_Float16)pv;
            }
        }
        #pragma unroll
        for (int dt = 0; dt < 4; ++dt) {
            int rv = dt * 16 + l16;
            #pragma unroll
            for (int t = 0; t < 4; ++t) {
                half4 vf = *(const half4*)&Vsc[rv * 64 +
                    (((t * 2 + (quad >> 1)) ^ (rv & 7)) << 3) + ((quad & 1) << 2)];
                o[dt] = __builtin_amdgcn_mfma_f32_16x16x16f16(vf, pt[t], o[dt], 0, 0, 0);
            }
        }
    }
    l_part += __shfl_xor(l_part, 16);
    l_part += __shfl_xor(l_part, 32);
    float inv = 1.f / l_part;
    #pragma unroll
    for (int dt = 0; dt < 4; ++dt) {
        floatx4 r;
        #pragma unroll
        for (int i = 0; i < 4; ++i) r[i] = o[dt][i] * inv;
        *(floatx4*)&out[((size_t)(b * 2048 + qrow + l16)) * 1024 + h * 64 + dt * 16 + quad * 4] = r;
    }
    #undef STAGE
}

extern "C" void kernel_launch(void* const* d_in, const int* in_sizes, int n_in,
                              void* d_out, int out_size, void* d_ws, size_t ws_size,
                              hipStream_t stream) {
    const float* x      = (const float*)d_in[0];
    const float* coords = (const float*)d_in[1];
    const float* mask   = (const float*)d_in[2];
    const float* Wqkv   = (const float*)d_in[3];
    const float* bqkv   = (const float*)d_in[4];
    const float* rw     = (const float*)d_in[5];
    float* out = (float*)d_out;

    char* ws = (char*)d_ws;
    _Float16* xh    = (_Float16*)(ws);               // dead after gemm; maskp reuses
    _Float16* maskp = (_Float16*)(ws);
    _Float16* Wt    = (_Float16*)(ws + 8388608);
    _Float16* qh    = (_Float16*)(ws + 14680064);
    _Float16* kh    = (_Float16*)(ws + 23068672);
    _Float16* vt    = (_Float16*)(ws + 31457280);
    float*    ncp   = (float*)(ws + 39845888);

    k_convert_x<<<2048, 256, 0, stream>>>(x, xh);
    k_transpose_w<<<dim3(96, 32), dim3(32, 8), 0, stream>>>(Wqkv, Wt);
    k_negcp<<<256, 256, 0, stream>>>(coords, rw, ncp);
    k_gemm<<<dim3(24, 32), 256, 0, stream>>>(xh, Wt, bqkv, qh, kh, vt);
    k_prep_mask<<<4096, 256, 0, stream>>>(mask, maskp);   // overwrites xh (now dead)
    k_attn<<<1024, 256, 0, stream>>>(qh, kh, vt, maskp, ncp, out);
}